// Round 20
// baseline (111.051 us; speedup 1.0000x reference)
//
#include <hip/hip_runtime.h>

#define N_NODES 50000
#define F 128
#define NBIN 98        /* dst>>9 : 512 nodes per bin */
#define BIN_NODES 512
#define BINCAP 10000   /* u32 slots per bin segment (avg 8163, max ~8620) */
#define NB_A 256       /* pass-A blocks, 3125 edges each */
#define NB_CV 6250     /* convert blocks */
#define NB_BT 128

typedef __attribute__((ext_vector_type(8))) short bf16x8;
typedef __attribute__((ext_vector_type(4))) float f32x4;
typedef __attribute__((ext_vector_type(4))) unsigned int u32x4;

__device__ __forceinline__ unsigned short f2bf(float f) {
    unsigned u = __float_as_uint(f);
    unsigned r = u + 0x7FFFu + ((u >> 16) & 1u);   // RNE
    return (unsigned short)(r >> 16);
}

// ---------------------------------------------------------------------------
// init: per-bin segment cursors
// ---------------------------------------------------------------------------
__global__ __launch_bounds__(128) void init_kernel(int* __restrict__ cursor)
{
    const int t = threadIdx.x;
    if (t < NBIN) cursor[t] = t * BINCAP;
}

// ---------------------------------------------------------------------------
// Fused: pass-A edge binning + x->bf16 convert + Bt build.
// ---------------------------------------------------------------------------
__global__ __launch_bounds__(256) void fused_prep_kernel(
    const float* __restrict__ x, unsigned short* __restrict__ xb,
    const int* __restrict__ src, const int* __restrict__ dst,
    int* __restrict__ cursor, unsigned* __restrict__ binbuf,
    const float* __restrict__ Wl, const float* __restrict__ Wr,
    unsigned short* __restrict__ Bt, int E)
{
    const int bid = blockIdx.x;
    const int t = threadIdx.x;

    if (bid < NB_A) {
        __shared__ int hist[NBIN], hist2[NBIN], base[NBIN];
        if (t < NBIN) { hist[t] = 0; hist2[t] = 0; }
        __syncthreads();

        const int e0 = bid * 3125;          // 256 * 3125 = 800000 exact
        for (int j = t; j < 3125; j += 256)
            atomicAdd(&hist[dst[e0 + j] >> 9], 1);
        __syncthreads();

        if (t < NBIN) base[t] = atomicAdd(&cursor[t], hist[t]);
        __syncthreads();

        for (int j = t; j < 3125; j += 256) {
            const int d = dst[e0 + j];
            const int s = src[e0 + j];
            const int b = d >> 9;
            const int r = atomicAdd(&hist2[b], 1);
            binbuf[base[b] + r] = (unsigned)s | ((unsigned)(d & 511) << 16);
        }
    } else if (bid < NB_A + NB_CV) {
        const int i = (bid - NB_A) * 256 + t;          // 1.6M float4 exact
        const float4 v = reinterpret_cast<const float4*>(x)[i];
        ushort4 o;
        o.x = f2bf(v.x); o.y = f2bf(v.y); o.z = f2bf(v.z); o.w = f2bf(v.w);
        reinterpret_cast<ushort4*>(xb)[i] = o;
    } else {
        const int gid = (bid - NB_A - NB_CV) * 256 + t;  // 32768 total
        const int n = gid >> 8;
        const int k = gid & 255;
        const float v = (k < F) ? Wl[k * F + n] : Wr[(k - F) * F + n];
        Bt[gid] = f2bf(v);
    }
}

// ---------------------------------------------------------------------------
// Pass B: one block (512 thr) per bin.  Counts degrees, scans in LDS,
// compacts the bin's edges, streams out a COMPACT CSR + start[] + deg[].
// ---------------------------------------------------------------------------
__global__ __launch_bounds__(512) void binscatter_kernel(
    const unsigned* __restrict__ binbuf, const int* __restrict__ cursor,
    unsigned short* __restrict__ csr, int* __restrict__ start,
    int* __restrict__ deg)
{
    __shared__ int degL[BIN_NODES], lofs[BIN_NODES], cnt2[BIN_NODES];
    __shared__ unsigned short lbc[BINCAP];       // 20 KB
    __shared__ int wsumS[8];
    __shared__ int pre[128];
    __shared__ int cbaseS;

    const int b = blockIdx.x, t = threadIdx.x;
    const int lane = t & 63, wid = t >> 6;

    degL[t] = 0; cnt2[t] = 0;
    // parallel 98-element exclusive prefix of bin counts -> cbase
    if (t < 128) {
        int v = (t < NBIN) ? (cursor[t] - t * BINCAP) : 0;
        int incl = v;
#pragma unroll
        for (int off = 1; off < 64; off <<= 1) {
            const int u = __shfl_up(incl, off, 64);
            if (lane >= off) incl += u;
        }
        pre[t] = incl;
    }
    __syncthreads();
    if (t == 0)
        cbaseS = (b == 0) ? 0 : ((b <= 64) ? pre[b - 1]
                                           : pre[63] + pre[b - 1]);
    const int lo = b * BINCAP;
    const int hi = cursor[b];
    const int n = hi - lo;

    for (int j = lo + t; j < hi; j += 512)
        atomicAdd(&degL[binbuf[j] >> 16], 1);
    __syncthreads();

    // scan degL[0..511] -> lofs (exclusive)
    {
        const int v = degL[t];
        int incl = v;
#pragma unroll
        for (int off = 1; off < 64; off <<= 1) {
            const int u = __shfl_up(incl, off, 64);
            if (lane >= off) incl += u;
        }
        if (lane == 63) wsumS[wid] = incl;
        __syncthreads();
        if (t == 0) {
            int run = 0;
#pragma unroll
            for (int w = 0; w < 8; ++w) { const int s = wsumS[w]; wsumS[w] = run; run += s; }
        }
        __syncthreads();
        lofs[t] = wsumS[wid] + incl - v;
    }
    __syncthreads();

    for (int j = lo + t; j < hi; j += 512) {
        const unsigned p = binbuf[j];
        const int dl = p >> 16;
        const int r = atomicAdd(&cnt2[dl], 1);
        lbc[lofs[dl] + r] = (unsigned short)(p & 0xFFFFu);
    }
    __syncthreads();

    const int gn0 = b * BIN_NODES;
    if (gn0 + t < N_NODES) {
        start[gn0 + t] = cbaseS + lofs[t];
        deg[gn0 + t] = degL[t];
    }
    for (int i = t; i < n; i += 512) csr[cbaseS + i] = lbc[i];
}

// ---------------------------------------------------------------------------
// FUSED aggregate + MFMA.  Block = 128 thr / 2 waves / 8 nodes -> 6250
// blocks (2x grid granularity vs r17; wave-slot cap 16 blocks/CU, grid
// offers 24.4/CU -> occupancy should ~2x from 47%).
// Phase 1 (gather): r17 economics — 16-lane group per node, 16B/lane
// u32x4 (1 VMEM instr per 4 rows per wave; r19 proved 4B/lane is
// issue-rate-bound), full index list preloaded into 4 regs.
// Phase 2 (MFMA): M=16 tile with rows 8..15 zero (2x MFMA work at 2%
// util — irrelevant); wave w covers cols [64w, 64w+64).
// ---------------------------------------------------------------------------
__global__ __launch_bounds__(128) void agg_out_kernel(
    const unsigned short* __restrict__ xb,
    const unsigned short* __restrict__ csr,
    const int* __restrict__ start,
    const int* __restrict__ deg,
    const unsigned short* __restrict__ Bt,
    const float* __restrict__ bias,
    float* __restrict__ out)
{
    __shared__ __align__(16) unsigned short mean_s[8][136];
    __shared__ float cs[8][132];

    const int t = threadIdx.x;
    const int w = t >> 6, lane = t & 63;
    const int g = lane >> 4, li = lane & 15;
    const int gg = w * 4 + g;                  // local node 0..7
    const int mbase = blockIdx.x * 8;          // 6250*8 = 50000 exact
    const int node = mbase + gg;

    // ---- Phase 1: aggregate this group's node ----
    const int cnt_total = deg[node];
    const int s0 = start[node];

    float a0 = 0.f, a1 = 0.f, a2 = 0.f, a3 = 0.f;
    float a4 = 0.f, a5 = 0.f, a6 = 0.f, a7 = 0.f;

    const int colu = li * 8;
    const int gbase = g * 16;

    // Preload the full index list (deg <= 64): 4 independent u16 loads.
    const int idx0 = (li      < cnt_total) ? (int)csr[s0 + li]      : 0;
    const int idx1 = (li + 16 < cnt_total) ? (int)csr[s0 + li + 16] : 0;
    const int idx2 = (li + 32 < cnt_total) ? (int)csr[s0 + li + 32] : 0;
    const int idx3 = (li + 48 < cnt_total) ? (int)csr[s0 + li + 48] : 0;

#define ACCV(v)                                   \
    {                                             \
        a0 += __uint_as_float((v).x << 16);       \
        a1 += __uint_as_float((v).x & 0xFFFF0000u); \
        a2 += __uint_as_float((v).y << 16);       \
        a3 += __uint_as_float((v).y & 0xFFFF0000u); \
        a4 += __uint_as_float((v).z << 16);       \
        a5 += __uint_as_float((v).z & 0xFFFF0000u); \
        a6 += __uint_as_float((v).w << 16);       \
        a7 += __uint_as_float((v).w & 0xFFFF0000u); \
    }

    for (int j = 0; j < cnt_total; j += 8) {
        const int c = j >> 4;
        int sel = idx0;
        sel = (c == 1) ? idx1 : sel;
        sel = (c == 2) ? idx2 : sel;
        sel = (c == 3) ? idx3 : sel;
        const int o = gbase + (j & 15);
        const int r0 = __shfl(sel, o + 0);
        const int r1 = __shfl(sel, o + 1);
        const int r2 = __shfl(sel, o + 2);
        const int r3 = __shfl(sel, o + 3);
        const int r4 = __shfl(sel, o + 4);
        const int r5 = __shfl(sel, o + 5);
        const int r6 = __shfl(sel, o + 6);
        const int r7 = __shfl(sel, o + 7);
        const u32x4 v0 = *reinterpret_cast<const u32x4*>(&xb[(size_t)r0 * F + colu]);
        const u32x4 v1 = *reinterpret_cast<const u32x4*>(&xb[(size_t)r1 * F + colu]);
        const u32x4 v2 = *reinterpret_cast<const u32x4*>(&xb[(size_t)r2 * F + colu]);
        const u32x4 v3 = *reinterpret_cast<const u32x4*>(&xb[(size_t)r3 * F + colu]);
        const u32x4 v4 = *reinterpret_cast<const u32x4*>(&xb[(size_t)r4 * F + colu]);
        const u32x4 v5 = *reinterpret_cast<const u32x4*>(&xb[(size_t)r5 * F + colu]);
        const u32x4 v6 = *reinterpret_cast<const u32x4*>(&xb[(size_t)r6 * F + colu]);
        const u32x4 v7 = *reinterpret_cast<const u32x4*>(&xb[(size_t)r7 * F + colu]);
        const int rem = cnt_total - j;
        ACCV(v0)
        if (rem > 1) ACCV(v1)
        if (rem > 2) ACCV(v2)
        if (rem > 3) ACCV(v3)
        if (rem > 4) ACCV(v4)
        if (rem > 5) ACCV(v5)
        if (rem > 6) ACCV(v6)
        if (rem > 7) ACCV(v7)
    }
#undef ACCV

    {
        const float inv = (cnt_total > 0) ? (1.0f / (float)cnt_total) : 1.0f;
        u32x4 u;
        u.x = (unsigned)f2bf(a0 * inv) | ((unsigned)f2bf(a1 * inv) << 16);
        u.y = (unsigned)f2bf(a2 * inv) | ((unsigned)f2bf(a3 * inv) << 16);
        u.z = (unsigned)f2bf(a4 * inv) | ((unsigned)f2bf(a5 * inv) << 16);
        u.w = (unsigned)f2bf(a6 * inv) | ((unsigned)f2bf(a7 * inv) << 16);
        *reinterpret_cast<u32x4*>(&mean_s[gg][colu]) = u;
    }
    __syncthreads();

    // ---- Phase 2: MFMA, wave w -> cols [64w, 64w+64); rows 8..15 zero ----
    const int kchunk = g * 8;
    const bool rok = li < 8;
    const int lrow = li & 7;

    bf16x8 a[8];
#pragma unroll
    for (int s = 0; s < 4; ++s) {
        a[s]     = (bf16x8){0, 0, 0, 0, 0, 0, 0, 0};
        a[s + 4] = (bf16x8){0, 0, 0, 0, 0, 0, 0, 0};
        if (rok) {
            a[s] = *reinterpret_cast<const bf16x8*>(
                &mean_s[lrow][s * 32 + kchunk]);
            a[s + 4] = *reinterpret_cast<const bf16x8*>(
                &xb[(size_t)(mbase + lrow) * F + s * 32 + kchunk]);
        }
    }

    f32x4 acc[4];
#pragma unroll
    for (int nt = 0; nt < 4; ++nt) acc[nt] = (f32x4){0.f, 0.f, 0.f, 0.f};

#pragma unroll
    for (int s = 0; s < 8; ++s) {
#pragma unroll
        for (int nt = 0; nt < 4; ++nt) {
            const bf16x8 bf = *reinterpret_cast<const bf16x8*>(
                &Bt[(size_t)((w * 4 + nt) * 16 + li) * 256 + s * 32 + kchunk]);
            acc[nt] = __builtin_amdgcn_mfma_f32_16x16x32_bf16(a[s], bf, acc[nt], 0, 0, 0);
        }
    }

#pragma unroll
    for (int nt = 0; nt < 4; ++nt) {
        const int col = (w * 4 + nt) * 16 + li;
        const float bv = bias[col];
#pragma unroll
        for (int r = 0; r < 4; ++r) {
            const int crow = g * 4 + r;
            if (crow < 8) cs[crow][col] = acc[nt][r] + bv;
        }
    }
    __syncthreads();

#pragma unroll
    for (int i = 0; i < 2; ++i) {
        const int idx = t + i * 128;          // 0..255 float4
        const int r = idx >> 5;               // 0..7
        const int c4 = (idx & 31) << 2;       // 0..124
        float4 v;
        v.x = cs[r][c4 + 0];
        v.y = cs[r][c4 + 1];
        v.z = cs[r][c4 + 2];
        v.w = cs[r][c4 + 3];
        *reinterpret_cast<float4*>(&out[(size_t)(mbase + r) * F + c4]) = v;
    }
}

extern "C" void kernel_launch(void* const* d_in, const int* in_sizes, int n_in,
                              void* d_out, int out_size, void* d_ws, size_t ws_size,
                              hipStream_t stream)
{
    const float* x  = (const float*)d_in[0];
    const int*   ei = (const int*)d_in[1];
    const float* Wl = (const float*)d_in[2];
    const float* Wr = (const float*)d_in[3];
    const float* b  = (const float*)d_in[4];
    float* out = (float*)d_out;

    const int E = in_sizes[1] / 2;           // 800000
    const int* src = ei;
    const int* dst = ei + E;

    // Workspace layout (16B-aligned chunks).
    int* cursor = (int*)d_ws;                                     // 128
    int* start  = cursor + 128;                                   // 50176
    int* deg    = start + 50176;                                  // 50176
    unsigned* binbuf = (unsigned*)(deg + 50176);                  // 980000
    unsigned short* csr = (unsigned short*)(binbuf + 980000);     // 800064 u16
    unsigned short* xb  = csr + 800064;                           // 6.4M u16
    unsigned short* Bt  = xb + (size_t)N_NODES * F;               // 32768 u16

    init_kernel<<<1, 128, 0, stream>>>(cursor);

    fused_prep_kernel<<<NB_A + NB_CV + NB_BT, 256, 0, stream>>>(
        x, xb, src, dst, cursor, binbuf, Wl, Wr, Bt, E);

    binscatter_kernel<<<NBIN, 512, 0, stream>>>(binbuf, cursor, csr, start, deg);

    agg_out_kernel<<<N_NODES / 8, 128, 0, stream>>>(
        xb, csr, start, deg, Bt, b, out);
}

// Round 21
// 87.480 us; speedup vs baseline: 1.2694x; 1.2694x over previous
//
#include <hip/hip_runtime.h>

#define N_NODES 50000
#define F 128
#define NBIN 98        /* dst>>9 : 512 nodes per bin */
#define BIN_NODES 512
#define BINCAP 10000   /* u32 slots per bin segment (avg 8163, max ~8620) */
#define NB_A 256       /* pass-A blocks, 3125 edges each */
#define NB_CV 6250     /* convert blocks */
#define NB_BT 128

typedef __attribute__((ext_vector_type(8))) short bf16x8;
typedef __attribute__((ext_vector_type(4))) float f32x4;
typedef __attribute__((ext_vector_type(4))) unsigned int u32x4;

__device__ __forceinline__ unsigned short f2bf(float f) {
    unsigned u = __float_as_uint(f);
    unsigned r = u + 0x7FFFu + ((u >> 16) & 1u);   // RNE
    return (unsigned short)(r >> 16);
}

// ---------------------------------------------------------------------------
// init: per-bin segment cursors
// ---------------------------------------------------------------------------
__global__ __launch_bounds__(128) void init_kernel(int* __restrict__ cursor)
{
    const int t = threadIdx.x;
    if (t < NBIN) cursor[t] = t * BINCAP;
}

// ---------------------------------------------------------------------------
// Fused: pass-A edge binning + x->bf16 convert + Bt build.
// ---------------------------------------------------------------------------
__global__ __launch_bounds__(256) void fused_prep_kernel(
    const float* __restrict__ x, unsigned short* __restrict__ xb,
    const int* __restrict__ src, const int* __restrict__ dst,
    int* __restrict__ cursor, unsigned* __restrict__ binbuf,
    const float* __restrict__ Wl, const float* __restrict__ Wr,
    unsigned short* __restrict__ Bt, int E)
{
    const int bid = blockIdx.x;
    const int t = threadIdx.x;

    if (bid < NB_A) {
        __shared__ int hist[NBIN], hist2[NBIN], base[NBIN];
        if (t < NBIN) { hist[t] = 0; hist2[t] = 0; }
        __syncthreads();

        const int e0 = bid * 3125;          // 256 * 3125 = 800000 exact
        for (int j = t; j < 3125; j += 256)
            atomicAdd(&hist[dst[e0 + j] >> 9], 1);
        __syncthreads();

        if (t < NBIN) base[t] = atomicAdd(&cursor[t], hist[t]);
        __syncthreads();

        for (int j = t; j < 3125; j += 256) {
            const int d = dst[e0 + j];
            const int s = src[e0 + j];
            const int b = d >> 9;
            const int r = atomicAdd(&hist2[b], 1);
            binbuf[base[b] + r] = (unsigned)s | ((unsigned)(d & 511) << 16);
        }
    } else if (bid < NB_A + NB_CV) {
        const int i = (bid - NB_A) * 256 + t;          // 1.6M float4 exact
        const float4 v = reinterpret_cast<const float4*>(x)[i];
        ushort4 o;
        o.x = f2bf(v.x); o.y = f2bf(v.y); o.z = f2bf(v.z); o.w = f2bf(v.w);
        reinterpret_cast<ushort4*>(xb)[i] = o;
    } else {
        const int gid = (bid - NB_A - NB_CV) * 256 + t;  // 32768 total
        const int n = gid >> 8;
        const int k = gid & 255;
        const float v = (k < F) ? Wl[k * F + n] : Wr[(k - F) * F + n];
        Bt[gid] = f2bf(v);
    }
}

// ---------------------------------------------------------------------------
// Pass B: one block (512 thr) per bin.  Counts degrees, scans in LDS,
// compacts the bin's edges, streams out a COMPACT CSR + start[] + deg[].
// ---------------------------------------------------------------------------
__global__ __launch_bounds__(512) void binscatter_kernel(
    const unsigned* __restrict__ binbuf, const int* __restrict__ cursor,
    unsigned short* __restrict__ csr, int* __restrict__ start,
    int* __restrict__ deg)
{
    __shared__ int degL[BIN_NODES], lofs[BIN_NODES], cnt2[BIN_NODES];
    __shared__ unsigned short lbc[BINCAP];       // 20 KB
    __shared__ int wsumS[8];
    __shared__ int pre[128];
    __shared__ int cbaseS;

    const int b = blockIdx.x, t = threadIdx.x;
    const int lane = t & 63, wid = t >> 6;

    degL[t] = 0; cnt2[t] = 0;
    // parallel 98-element exclusive prefix of bin counts -> cbase
    if (t < 128) {
        int v = (t < NBIN) ? (cursor[t] - t * BINCAP) : 0;
        int incl = v;
#pragma unroll
        for (int off = 1; off < 64; off <<= 1) {
            const int u = __shfl_up(incl, off, 64);
            if (lane >= off) incl += u;
        }
        pre[t] = incl;
    }
    __syncthreads();
    if (t == 0)
        cbaseS = (b == 0) ? 0 : ((b <= 64) ? pre[b - 1]
                                           : pre[63] + pre[b - 1]);
    const int lo = b * BINCAP;
    const int hi = cursor[b];
    const int n = hi - lo;

    for (int j = lo + t; j < hi; j += 512)
        atomicAdd(&degL[binbuf[j] >> 16], 1);
    __syncthreads();

    // scan degL[0..511] -> lofs (exclusive)
    {
        const int v = degL[t];
        int incl = v;
#pragma unroll
        for (int off = 1; off < 64; off <<= 1) {
            const int u = __shfl_up(incl, off, 64);
            if (lane >= off) incl += u;
        }
        if (lane == 63) wsumS[wid] = incl;
        __syncthreads();
        if (t == 0) {
            int run = 0;
#pragma unroll
            for (int w = 0; w < 8; ++w) { const int s = wsumS[w]; wsumS[w] = run; run += s; }
        }
        __syncthreads();
        lofs[t] = wsumS[wid] + incl - v;
    }
    __syncthreads();

    for (int j = lo + t; j < hi; j += 512) {
        const unsigned p = binbuf[j];
        const int dl = p >> 16;
        const int r = atomicAdd(&cnt2[dl], 1);
        lbc[lofs[dl] + r] = (unsigned short)(p & 0xFFFFu);
    }
    __syncthreads();

    const int gn0 = b * BIN_NODES;
    if (gn0 + t < N_NODES) {
        start[gn0 + t] = cbaseS + lofs[t];
        deg[gn0 + t] = degL[t];
    }
    for (int i = t; i < n; i += 512) csr[cbaseS + i] = lbc[i];
}

// ---------------------------------------------------------------------------
// FUSED aggregate + MFMA.  Block = 256 thr / 4 waves / 16 nodes (r17
// structure, best measured).  Phase-1 gather is now SOFTWARE-PIPELINED
// 2-DEEP: two named register batches (A/B, 8 x u32x4 each) alternate —
// while batch A is being consumed, batch B's 8 loads are in flight
// (compiler emits vmcnt(8), not vmcnt(0)).  Doubles per-wave outstanding
// latency coverage, attacking the ~1000cy/batch serialization seen in
// r17 (one batch in flight per wave).
// ---------------------------------------------------------------------------
__global__ __launch_bounds__(256) void agg_out_kernel(
    const unsigned short* __restrict__ xb,
    const unsigned short* __restrict__ csr,
    const int* __restrict__ start,
    const int* __restrict__ deg,
    const unsigned short* __restrict__ Bt,
    const float* __restrict__ bias,
    float* __restrict__ out)
{
    __shared__ __align__(16) unsigned short mean_s[16][136];
    __shared__ float cs[16][132];

    const int t = threadIdx.x;
    const int w = t >> 6, lane = t & 63;
    const int g = lane >> 4, li = lane & 15;
    const int ln = w * 4 + g;                  // local node 0..15
    const int mbase = blockIdx.x * 16;
    const int node = mbase + ln;

    // ---- Phase 1: aggregate this group's node (2-deep pipelined) ----
    const int cnt_total = deg[node];
    const int s0 = start[node];

    float a0 = 0.f, a1 = 0.f, a2 = 0.f, a3 = 0.f;
    float a4 = 0.f, a5 = 0.f, a6 = 0.f, a7 = 0.f;

    const int colu = li * 8;
    const int gbase = g * 16;

    // Preload the full index list (deg <= 64): 4 independent u16 loads.
    const int idx0 = (li      < cnt_total) ? (int)csr[s0 + li]      : 0;
    const int idx1 = (li + 16 < cnt_total) ? (int)csr[s0 + li + 16] : 0;
    const int idx2 = (li + 32 < cnt_total) ? (int)csr[s0 + li + 32] : 0;
    const int idx3 = (li + 48 < cnt_total) ? (int)csr[s0 + li + 48] : 0;

    u32x4 A0, A1, A2, A3, A4, A5, A6, A7;
    u32x4 B0, B1, B2, B3, B4, B5, B6, B7;

#define ISSUE(R0, R1, R2, R3, R4, R5, R6, R7, b)                            \
    {                                                                       \
        const int c_ = (b) >> 1;                                            \
        int sel_ = idx0;                                                    \
        sel_ = (c_ == 1) ? idx1 : sel_;                                     \
        sel_ = (c_ == 2) ? idx2 : sel_;                                     \
        sel_ = (c_ == 3) ? idx3 : sel_;                                     \
        const int o_ = gbase + (((b) & 1) << 3);                            \
        const int r0_ = __shfl(sel_, o_ + 0);                               \
        const int r1_ = __shfl(sel_, o_ + 1);                               \
        const int r2_ = __shfl(sel_, o_ + 2);                               \
        const int r3_ = __shfl(sel_, o_ + 3);                               \
        const int r4_ = __shfl(sel_, o_ + 4);                               \
        const int r5_ = __shfl(sel_, o_ + 5);                               \
        const int r6_ = __shfl(sel_, o_ + 6);                               \
        const int r7_ = __shfl(sel_, o_ + 7);                               \
        R0 = *reinterpret_cast<const u32x4*>(&xb[(size_t)r0_ * F + colu]);  \
        R1 = *reinterpret_cast<const u32x4*>(&xb[(size_t)r1_ * F + colu]);  \
        R2 = *reinterpret_cast<const u32x4*>(&xb[(size_t)r2_ * F + colu]);  \
        R3 = *reinterpret_cast<const u32x4*>(&xb[(size_t)r3_ * F + colu]);  \
        R4 = *reinterpret_cast<const u32x4*>(&xb[(size_t)r4_ * F + colu]);  \
        R5 = *reinterpret_cast<const u32x4*>(&xb[(size_t)r5_ * F + colu]);  \
        R6 = *reinterpret_cast<const u32x4*>(&xb[(size_t)r6_ * F + colu]);  \
        R7 = *reinterpret_cast<const u32x4*>(&xb[(size_t)r7_ * F + colu]);  \
    }

#define ACCV(v)                                     \
    {                                               \
        a0 += __uint_as_float((v).x << 16);         \
        a1 += __uint_as_float((v).x & 0xFFFF0000u); \
        a2 += __uint_as_float((v).y << 16);         \
        a3 += __uint_as_float((v).y & 0xFFFF0000u); \
        a4 += __uint_as_float((v).z << 16);         \
        a5 += __uint_as_float((v).z & 0xFFFF0000u); \
        a6 += __uint_as_float((v).w << 16);         \
        a7 += __uint_as_float((v).w & 0xFFFF0000u); \
    }

#define CONSUME(R0, R1, R2, R3, R4, R5, R6, R7, b)  \
    {                                               \
        const int rem_ = cnt_total - (b) * 8;       \
        ACCV(R0)                                    \
        if (rem_ > 1) ACCV(R1)                      \
        if (rem_ > 2) ACCV(R2)                      \
        if (rem_ > 3) ACCV(R3)                      \
        if (rem_ > 4) ACCV(R4)                      \
        if (rem_ > 5) ACCV(R5)                      \
        if (rem_ > 6) ACCV(R6)                      \
        if (rem_ > 7) ACCV(R7)                      \
    }

    const int nb = (cnt_total + 7) >> 3;       // 0..8 batches of 8 rows

    if (nb > 0) {
        ISSUE(A0, A1, A2, A3, A4, A5, A6, A7, 0)
        if (nb > 1) ISSUE(B0, B1, B2, B3, B4, B5, B6, B7, 1)

        for (int b = 0; b < nb; b += 2) {
            CONSUME(A0, A1, A2, A3, A4, A5, A6, A7, b)
            if (b + 2 < nb) ISSUE(A0, A1, A2, A3, A4, A5, A6, A7, b + 2)
            if (b + 1 < nb) {
                CONSUME(B0, B1, B2, B3, B4, B5, B6, B7, b + 1)
                if (b + 3 < nb) ISSUE(B0, B1, B2, B3, B4, B5, B6, B7, b + 3)
            }
        }
    }
#undef ISSUE
#undef ACCV
#undef CONSUME

    {
        const float inv = (cnt_total > 0) ? (1.0f / (float)cnt_total) : 1.0f;
        u32x4 u;
        u.x = (unsigned)f2bf(a0 * inv) | ((unsigned)f2bf(a1 * inv) << 16);
        u.y = (unsigned)f2bf(a2 * inv) | ((unsigned)f2bf(a3 * inv) << 16);
        u.z = (unsigned)f2bf(a4 * inv) | ((unsigned)f2bf(a5 * inv) << 16);
        u.w = (unsigned)f2bf(a6 * inv) | ((unsigned)f2bf(a7 * inv) << 16);
        *reinterpret_cast<u32x4*>(&mean_s[ln][colu]) = u;
    }
    __syncthreads();

    // ---- Phase 2: MFMA, wave w -> cols [32w, 32w+32) ----
    const int arow = mbase + li;
    const int kchunk = g * 8;

    bf16x8 a[8];
#pragma unroll
    for (int s = 0; s < 4; ++s) {
        a[s] = *reinterpret_cast<const bf16x8*>(&mean_s[li][s * 32 + kchunk]);
        a[s + 4] = *reinterpret_cast<const bf16x8*>(
            &xb[(size_t)arow * F + s * 32 + kchunk]);
    }

    f32x4 acc[2];
    acc[0] = (f32x4){0.f, 0.f, 0.f, 0.f};
    acc[1] = (f32x4){0.f, 0.f, 0.f, 0.f};

#pragma unroll
    for (int s = 0; s < 8; ++s) {
#pragma unroll
        for (int nt = 0; nt < 2; ++nt) {
            const bf16x8 bf = *reinterpret_cast<const bf16x8*>(
                &Bt[(size_t)((w * 2 + nt) * 16 + li) * 256 + s * 32 + kchunk]);
            acc[nt] = __builtin_amdgcn_mfma_f32_16x16x32_bf16(a[s], bf, acc[nt], 0, 0, 0);
        }
    }

#pragma unroll
    for (int nt = 0; nt < 2; ++nt) {
        const int col = (w * 2 + nt) * 16 + li;
        const float bv = bias[col];
#pragma unroll
        for (int r = 0; r < 4; ++r)
            cs[g * 4 + r][col] = acc[nt][r] + bv;
    }
    __syncthreads();

#pragma unroll
    for (int i = 0; i < 2; ++i) {
        const int idx = t + i * 256;          // 0..511
        const int r = idx >> 5;               // 0..15
        const int c4 = (idx & 31) << 2;       // 0..124
        float4 v;
        v.x = cs[r][c4 + 0];
        v.y = cs[r][c4 + 1];
        v.z = cs[r][c4 + 2];
        v.w = cs[r][c4 + 3];
        *reinterpret_cast<float4*>(&out[(size_t)(mbase + r) * F + c4]) = v;
    }
}

extern "C" void kernel_launch(void* const* d_in, const int* in_sizes, int n_in,
                              void* d_out, int out_size, void* d_ws, size_t ws_size,
                              hipStream_t stream)
{
    const float* x  = (const float*)d_in[0];
    const int*   ei = (const int*)d_in[1];
    const float* Wl = (const float*)d_in[2];
    const float* Wr = (const float*)d_in[3];
    const float* b  = (const float*)d_in[4];
    float* out = (float*)d_out;

    const int E = in_sizes[1] / 2;           // 800000
    const int* src = ei;
    const int* dst = ei + E;

    // Workspace layout (16B-aligned chunks).
    int* cursor = (int*)d_ws;                                     // 128
    int* start  = cursor + 128;                                   // 50176
    int* deg    = start + 50176;                                  // 50176
    unsigned* binbuf = (unsigned*)(deg + 50176);                  // 980000
    unsigned short* csr = (unsigned short*)(binbuf + 980000);     // 800064 u16
    unsigned short* xb  = csr + 800064;                           // 6.4M u16
    unsigned short* Bt  = xb + (size_t)N_NODES * F;               // 32768 u16

    init_kernel<<<1, 128, 0, stream>>>(cursor);

    fused_prep_kernel<<<NB_A + NB_CV + NB_BT, 256, 0, stream>>>(
        x, xb, src, dst, cursor, binbuf, Wl, Wr, Bt, E);

    binscatter_kernel<<<NBIN, 512, 0, stream>>>(binbuf, cursor, csr, start, deg);

    agg_out_kernel<<<N_NODES / 16, 256, 0, stream>>>(
        xb, csr, start, deg, Bt, b, out);
}

// Round 22
// 87.365 us; speedup vs baseline: 1.2711x; 1.0013x over previous
//
#include <hip/hip_runtime.h>

#define N_NODES 50000
#define F 128
#define NBIN 98        /* dst>>9 : 512 nodes per bin */
#define BIN_NODES 512
#define BINCAP 10000   /* u32 slots per bin segment (avg 8163, max ~8620) */
#define NB_A 256       /* pass-A blocks, 3125 edges each */
#define NB_CV 6250     /* convert blocks */
#define NB_BT 128

typedef __attribute__((ext_vector_type(8))) short bf16x8;
typedef __attribute__((ext_vector_type(4))) float f32x4;
typedef __attribute__((ext_vector_type(4))) unsigned int u32x4;

__device__ __forceinline__ unsigned short f2bf(float f) {
    unsigned u = __float_as_uint(f);
    unsigned r = u + 0x7FFFu + ((u >> 16) & 1u);   // RNE
    return (unsigned short)(r >> 16);
}

// ---------------------------------------------------------------------------
// init: per-bin segment cursors
// ---------------------------------------------------------------------------
__global__ __launch_bounds__(128) void init_kernel(int* __restrict__ cursor)
{
    const int t = threadIdx.x;
    if (t < NBIN) cursor[t] = t * BINCAP;
}

// ---------------------------------------------------------------------------
// Fused: pass-A edge binning + x->bf16 convert + Bt build.
// ---------------------------------------------------------------------------
__global__ __launch_bounds__(256) void fused_prep_kernel(
    const float* __restrict__ x, unsigned short* __restrict__ xb,
    const int* __restrict__ src, const int* __restrict__ dst,
    int* __restrict__ cursor, unsigned* __restrict__ binbuf,
    const float* __restrict__ Wl, const float* __restrict__ Wr,
    unsigned short* __restrict__ Bt, int E)
{
    const int bid = blockIdx.x;
    const int t = threadIdx.x;

    if (bid < NB_A) {
        __shared__ int hist[NBIN], hist2[NBIN], base[NBIN];
        if (t < NBIN) { hist[t] = 0; hist2[t] = 0; }
        __syncthreads();

        const int e0 = bid * 3125;          // 256 * 3125 = 800000 exact
        for (int j = t; j < 3125; j += 256)
            atomicAdd(&hist[dst[e0 + j] >> 9], 1);
        __syncthreads();

        if (t < NBIN) base[t] = atomicAdd(&cursor[t], hist[t]);
        __syncthreads();

        for (int j = t; j < 3125; j += 256) {
            const int d = dst[e0 + j];
            const int s = src[e0 + j];
            const int b = d >> 9;
            const int r = atomicAdd(&hist2[b], 1);
            binbuf[base[b] + r] = (unsigned)s | ((unsigned)(d & 511) << 16);
        }
    } else if (bid < NB_A + NB_CV) {
        const int i = (bid - NB_A) * 256 + t;          // 1.6M float4 exact
        const float4 v = reinterpret_cast<const float4*>(x)[i];
        ushort4 o;
        o.x = f2bf(v.x); o.y = f2bf(v.y); o.z = f2bf(v.z); o.w = f2bf(v.w);
        reinterpret_cast<ushort4*>(xb)[i] = o;
    } else {
        const int gid = (bid - NB_A - NB_CV) * 256 + t;  // 32768 total
        const int n = gid >> 8;
        const int k = gid & 255;
        const float v = (k < F) ? Wl[k * F + n] : Wr[(k - F) * F + n];
        Bt[gid] = f2bf(v);
    }
}

// ---------------------------------------------------------------------------
// Pass B: one block (512 thr) per bin.  Counts degrees, scans in LDS,
// compacts the bin's edges, streams out a COMPACT CSR + start[] + deg[].
// ---------------------------------------------------------------------------
__global__ __launch_bounds__(512) void binscatter_kernel(
    const unsigned* __restrict__ binbuf, const int* __restrict__ cursor,
    unsigned short* __restrict__ csr, int* __restrict__ start,
    int* __restrict__ deg)
{
    __shared__ int degL[BIN_NODES], lofs[BIN_NODES], cnt2[BIN_NODES];
    __shared__ unsigned short lbc[BINCAP];       // 20 KB
    __shared__ int wsumS[8];
    __shared__ int pre[128];
    __shared__ int cbaseS;

    const int b = blockIdx.x, t = threadIdx.x;
    const int lane = t & 63, wid = t >> 6;

    degL[t] = 0; cnt2[t] = 0;
    // parallel 98-element exclusive prefix of bin counts -> cbase
    if (t < 128) {
        int v = (t < NBIN) ? (cursor[t] - t * BINCAP) : 0;
        int incl = v;
#pragma unroll
        for (int off = 1; off < 64; off <<= 1) {
            const int u = __shfl_up(incl, off, 64);
            if (lane >= off) incl += u;
        }
        pre[t] = incl;
    }
    __syncthreads();
    if (t == 0)
        cbaseS = (b == 0) ? 0 : ((b <= 64) ? pre[b - 1]
                                           : pre[63] + pre[b - 1]);
    const int lo = b * BINCAP;
    const int hi = cursor[b];
    const int n = hi - lo;

    for (int j = lo + t; j < hi; j += 512)
        atomicAdd(&degL[binbuf[j] >> 16], 1);
    __syncthreads();

    // scan degL[0..511] -> lofs (exclusive)
    {
        const int v = degL[t];
        int incl = v;
#pragma unroll
        for (int off = 1; off < 64; off <<= 1) {
            const int u = __shfl_up(incl, off, 64);
            if (lane >= off) incl += u;
        }
        if (lane == 63) wsumS[wid] = incl;
        __syncthreads();
        if (t == 0) {
            int run = 0;
#pragma unroll
            for (int w = 0; w < 8; ++w) { const int s = wsumS[w]; wsumS[w] = run; run += s; }
        }
        __syncthreads();
        lofs[t] = wsumS[wid] + incl - v;
    }
    __syncthreads();

    for (int j = lo + t; j < hi; j += 512) {
        const unsigned p = binbuf[j];
        const int dl = p >> 16;
        const int r = atomicAdd(&cnt2[dl], 1);
        lbc[lofs[dl] + r] = (unsigned short)(p & 0xFFFFu);
    }
    __syncthreads();

    const int gn0 = b * BIN_NODES;
    if (gn0 + t < N_NODES) {
        start[gn0 + t] = cbaseS + lofs[t];
        deg[gn0 + t] = degL[t];
    }
    for (int i = t; i < n; i += 512) csr[cbaseS + i] = lbc[i];
}

// ---------------------------------------------------------------------------
// FUSED aggregate + MFMA.  Block = 256 thr / 4 waves / 16 nodes (r17
// structure, best measured: agg 55.2us @ 47% occ, VGPR 40).
// NEW (T14-style): phase-2's x A-fragments (own row, 4 x 16B, independent
// of the gather) are ISSUED AT KERNEL ENTRY and consumed after the
// barrier — their ~500cy latency hides under the entire gather phase.
// Phase 1 (gather): 16-lane group per node, 16B/lane u32x4, full index
// list preloaded into 4 regs, 8 rows in flight.
// Phase 2 (MFMA): wave w -> cols [32w,32w+32); mean from LDS; C staged
// in LDS, coalesced 512B row writes.
// ---------------------------------------------------------------------------
__global__ __launch_bounds__(256) void agg_out_kernel(
    const unsigned short* __restrict__ xb,
    const unsigned short* __restrict__ csr,
    const int* __restrict__ start,
    const int* __restrict__ deg,
    const unsigned short* __restrict__ Bt,
    const float* __restrict__ bias,
    float* __restrict__ out)
{
    __shared__ __align__(16) unsigned short mean_s[16][136];
    __shared__ float cs[16][132];

    const int t = threadIdx.x;
    const int w = t >> 6, lane = t & 63;
    const int g = lane >> 4, li = lane & 15;
    const int ln = w * 4 + g;                  // local node 0..15
    const int mbase = blockIdx.x * 16;
    const int node = mbase + ln;
    const int arow = mbase + li;
    const int kchunk = g * 8;

    // ---- Early issue: phase-2 x fragments (independent of gather) ----
    bf16x8 ax0 = *reinterpret_cast<const bf16x8*>(&xb[(size_t)arow * F + 0  + kchunk]);
    bf16x8 ax1 = *reinterpret_cast<const bf16x8*>(&xb[(size_t)arow * F + 32 + kchunk]);
    bf16x8 ax2 = *reinterpret_cast<const bf16x8*>(&xb[(size_t)arow * F + 64 + kchunk]);
    bf16x8 ax3 = *reinterpret_cast<const bf16x8*>(&xb[(size_t)arow * F + 96 + kchunk]);

    // ---- Phase 1: aggregate this group's node ----
    const int cnt_total = deg[node];
    const int s0 = start[node];

    float a0 = 0.f, a1 = 0.f, a2 = 0.f, a3 = 0.f;
    float a4 = 0.f, a5 = 0.f, a6 = 0.f, a7 = 0.f;

    const int colu = li * 8;
    const int gbase = g * 16;

    // Preload the full index list (deg <= 64): 4 independent u16 loads.
    const int idx0 = (li      < cnt_total) ? (int)csr[s0 + li]      : 0;
    const int idx1 = (li + 16 < cnt_total) ? (int)csr[s0 + li + 16] : 0;
    const int idx2 = (li + 32 < cnt_total) ? (int)csr[s0 + li + 32] : 0;
    const int idx3 = (li + 48 < cnt_total) ? (int)csr[s0 + li + 48] : 0;

#define ACCV(v)                                   \
    {                                             \
        a0 += __uint_as_float((v).x << 16);       \
        a1 += __uint_as_float((v).x & 0xFFFF0000u); \
        a2 += __uint_as_float((v).y << 16);       \
        a3 += __uint_as_float((v).y & 0xFFFF0000u); \
        a4 += __uint_as_float((v).z << 16);       \
        a5 += __uint_as_float((v).z & 0xFFFF0000u); \
        a6 += __uint_as_float((v).w << 16);       \
        a7 += __uint_as_float((v).w & 0xFFFF0000u); \
    }

    for (int j = 0; j < cnt_total; j += 8) {
        const int c = j >> 4;
        int sel = idx0;
        sel = (c == 1) ? idx1 : sel;
        sel = (c == 2) ? idx2 : sel;
        sel = (c == 3) ? idx3 : sel;
        const int o = gbase + (j & 15);
        const int r0 = __shfl(sel, o + 0);
        const int r1 = __shfl(sel, o + 1);
        const int r2 = __shfl(sel, o + 2);
        const int r3 = __shfl(sel, o + 3);
        const int r4 = __shfl(sel, o + 4);
        const int r5 = __shfl(sel, o + 5);
        const int r6 = __shfl(sel, o + 6);
        const int r7 = __shfl(sel, o + 7);
        const u32x4 v0 = *reinterpret_cast<const u32x4*>(&xb[(size_t)r0 * F + colu]);
        const u32x4 v1 = *reinterpret_cast<const u32x4*>(&xb[(size_t)r1 * F + colu]);
        const u32x4 v2 = *reinterpret_cast<const u32x4*>(&xb[(size_t)r2 * F + colu]);
        const u32x4 v3 = *reinterpret_cast<const u32x4*>(&xb[(size_t)r3 * F + colu]);
        const u32x4 v4 = *reinterpret_cast<const u32x4*>(&xb[(size_t)r4 * F + colu]);
        const u32x4 v5 = *reinterpret_cast<const u32x4*>(&xb[(size_t)r5 * F + colu]);
        const u32x4 v6 = *reinterpret_cast<const u32x4*>(&xb[(size_t)r6 * F + colu]);
        const u32x4 v7 = *reinterpret_cast<const u32x4*>(&xb[(size_t)r7 * F + colu]);
        const int rem = cnt_total - j;
        ACCV(v0)
        if (rem > 1) ACCV(v1)
        if (rem > 2) ACCV(v2)
        if (rem > 3) ACCV(v3)
        if (rem > 4) ACCV(v4)
        if (rem > 5) ACCV(v5)
        if (rem > 6) ACCV(v6)
        if (rem > 7) ACCV(v7)
    }
#undef ACCV

    {
        const float inv = (cnt_total > 0) ? (1.0f / (float)cnt_total) : 1.0f;
        u32x4 u;
        u.x = (unsigned)f2bf(a0 * inv) | ((unsigned)f2bf(a1 * inv) << 16);
        u.y = (unsigned)f2bf(a2 * inv) | ((unsigned)f2bf(a3 * inv) << 16);
        u.z = (unsigned)f2bf(a4 * inv) | ((unsigned)f2bf(a5 * inv) << 16);
        u.w = (unsigned)f2bf(a6 * inv) | ((unsigned)f2bf(a7 * inv) << 16);
        *reinterpret_cast<u32x4*>(&mean_s[ln][colu]) = u;
    }
    __syncthreads();

    // ---- Phase 2: MFMA, wave w -> cols [32w, 32w+32) ----
    bf16x8 a[8];
#pragma unroll
    for (int s = 0; s < 4; ++s)
        a[s] = *reinterpret_cast<const bf16x8*>(&mean_s[li][s * 32 + kchunk]);
    a[4] = ax0; a[5] = ax1; a[6] = ax2; a[7] = ax3;

    f32x4 acc[2];
    acc[0] = (f32x4){0.f, 0.f, 0.f, 0.f};
    acc[1] = (f32x4){0.f, 0.f, 0.f, 0.f};

#pragma unroll
    for (int s = 0; s < 8; ++s) {
#pragma unroll
        for (int nt = 0; nt < 2; ++nt) {
            const bf16x8 bf = *reinterpret_cast<const bf16x8*>(
                &Bt[(size_t)((w * 2 + nt) * 16 + li) * 256 + s * 32 + kchunk]);
            acc[nt] = __builtin_amdgcn_mfma_f32_16x16x32_bf16(a[s], bf, acc[nt], 0, 0, 0);
        }
    }

#pragma unroll
    for (int nt = 0; nt < 2; ++nt) {
        const int col = (w * 2 + nt) * 16 + li;
        const float bv = bias[col];
#pragma unroll
        for (int r = 0; r < 4; ++r)
            cs[g * 4 + r][col] = acc[nt][r] + bv;
    }
    __syncthreads();

#pragma unroll
    for (int i = 0; i < 2; ++i) {
        const int idx = t + i * 256;          // 0..511
        const int r = idx >> 5;               // 0..15
        const int c4 = (idx & 31) << 2;       // 0..124
        float4 v;
        v.x = cs[r][c4 + 0];
        v.y = cs[r][c4 + 1];
        v.z = cs[r][c4 + 2];
        v.w = cs[r][c4 + 3];
        *reinterpret_cast<float4*>(&out[(size_t)(mbase + r) * F + c4]) = v;
    }
}

extern "C" void kernel_launch(void* const* d_in, const int* in_sizes, int n_in,
                              void* d_out, int out_size, void* d_ws, size_t ws_size,
                              hipStream_t stream)
{
    const float* x  = (const float*)d_in[0];
    const int*   ei = (const int*)d_in[1];
    const float* Wl = (const float*)d_in[2];
    const float* Wr = (const float*)d_in[3];
    const float* b  = (const float*)d_in[4];
    float* out = (float*)d_out;

    const int E = in_sizes[1] / 2;           // 800000
    const int* src = ei;
    const int* dst = ei + E;

    // Workspace layout (16B-aligned chunks).
    int* cursor = (int*)d_ws;                                     // 128
    int* start  = cursor + 128;                                   // 50176
    int* deg    = start + 50176;                                  // 50176
    unsigned* binbuf = (unsigned*)(deg + 50176);                  // 980000
    unsigned short* csr = (unsigned short*)(binbuf + 980000);     // 800064 u16
    unsigned short* xb  = csr + 800064;                           // 6.4M u16
    unsigned short* Bt  = xb + (size_t)N_NODES * F;               // 32768 u16

    init_kernel<<<1, 128, 0, stream>>>(cursor);

    fused_prep_kernel<<<NB_A + NB_CV + NB_BT, 256, 0, stream>>>(
        x, xb, src, dst, cursor, binbuf, Wl, Wr, Bt, E);

    binscatter_kernel<<<NBIN, 512, 0, stream>>>(binbuf, cursor, csr, start, deg);

    agg_out_kernel<<<N_NODES / 16, 256, 0, stream>>>(
        xb, csr, start, deg, Bt, b, out);
}